// Round 7
// baseline (142.242 us; speedup 1.0000x reference)
//
#include <hip/hip_runtime.h>
#include <hip/hip_bf16.h>

// Fused Swin window attention for MI355X (gfx950) — round 7 (= r6 + bias fix).
// One block per 8x8 window (2048 blocks x 256 threads, 4 waves), 2 blocks/CU.
// r6 failed: in the S^T orientation the q-pixel axis moved to the C-frag
// COLUMN (w*16 + l15), but the bias load dropped the wave offset (used
// l15*64 instead of (w*16+l15)*64) -> waves 1-3 used wave-0 bias rows.
// r7 fixes that single line. Structure (from r6):
//   * Q/K GEMM computes transposed (mfma(W,x)) -> q/k stores are b64-packed.
//   * QK^T swapped (mfma(k,q) = S^T) -> P row lives at lane=l15 -> b64 stores.
//   * PV swapped (mfma(vT,P^T) = oh^T) + osum^T = mfma(ones,P^T): row-sum
//     replicated per lane -> single v_rcp, lane-local normalize, b64 oh store.
//   * XOR swizzle col ^= (row&7)<<3 on all LDS tiles -> uniform bank load.
// LDS footprint: 79,872 B -> 2 blocks/CU.

typedef __attribute__((ext_vector_type(8))) short bf16x8;
typedef __attribute__((ext_vector_type(4))) float f32x4;

__device__ __forceinline__ f32x4 mfma16(bf16x8 a, bf16x8 b, f32x4 c) {
  return __builtin_amdgcn_mfma_f32_16x16x32_bf16(a, b, c, 0, 0, 0);
}

__device__ __forceinline__ unsigned short f2bf(float f) {
  __hip_bfloat16 h = __float2bfloat16(f);
  return *reinterpret_cast<unsigned short*>(&h);
}

__device__ __forceinline__ uint2 pack4(float a, float b, float c, float d) {
  union { unsigned short u[4]; uint2 v; } pk;
  pk.u[0] = f2bf(a); pk.u[1] = f2bf(b); pk.u[2] = f2bf(c); pk.u[3] = f2bf(d);
  return pk.v;
}

#define LOG2E 1.4426950408889634f
#define EXPSCALE (0.17677669529663687f * 1.4426950408889634f)

// LDS layout (ushort elements)
#define XSTR 264     // x / q / k row stride (64 rows)
#define VSTR 72      // vT row stride (256 rows)
#define SSTR 72      // per-wave scratch row stride (16 rows)
#define OFF_A  0     // region A: x (64x264) then vT (256x72=18432)
#define OFF_B  18432 // region B: q then k (64x264=16896)
#define OFF_SC 35328 // scratch: 4 waves x 16 x 72 = 4608
#define SMEM_ELTS 39936  // 79,872 bytes -> 2 blocks/CU

// Weight tiled layout: elem(n,k) -> ((((n>>4)*8+(k>>5))*4+((k>>3)&3))*16+(n&15))*8+(k&7)
__global__ void prep_kernel(const float* __restrict__ w_qkv,
                            const float* __restrict__ w_out,
                            const float* __restrict__ pos_emb,
                            unsigned short* __restrict__ wqkvT,
                            unsigned short* __restrict__ woutT,
                            float* __restrict__ bias64) {
  const int stride = gridDim.x * blockDim.x;
  const int tid = blockIdx.x * blockDim.x + threadIdx.x;
  for (int i = tid; i < 768 * 256; i += stride) {
    int n = i >> 8, k = i & 255;
    int off = ((((n >> 4) * 8 + (k >> 5)) * 4 + ((k >> 3) & 3)) * 16 + (n & 15)) * 8 + (k & 7);
    wqkvT[off] = f2bf(w_qkv[k * 768 + n]);
  }
  for (int i = tid; i < 256 * 256; i += stride) {
    int n = i >> 8, k = i & 255;
    int off = ((((n >> 4) * 8 + (k >> 5)) * 4 + ((k >> 3) & 3)) * 16 + (n & 15)) * 8 + (k & 7);
    woutT[off] = f2bf(w_out[k * 256 + n]);
  }
  for (int i = tid; i < 64 * 64; i += stride) {
    int a = i >> 6, b = i & 63;
    int d0 = (b >> 3) - (a >> 3) + 7;
    int d1 = (b & 7) - (a & 7) + 7;
    bias64[i] = pos_emb[d0 * 15 + d1] * LOG2E;   // pre-scaled for exp2
  }
}

// QKV GEMM, software-pipelined k-steps. SWAP=true computes the transposed
// tile (A=weight frag, B=x frag) so the C-frag row axis = output feature.
template <bool SWAP>
__device__ __forceinline__ void qkv_gemm(f32x4 (&acc)[4][4],
                                         const unsigned short* __restrict__ x_lds,
                                         const unsigned short* __restrict__ wqkvT,
                                         int col0, int l15, int lq, int swz) {
  const f32x4 zero4 = {0.f, 0.f, 0.f, 0.f};
#pragma unroll
  for (int rt = 0; rt < 4; ++rt)
#pragma unroll
    for (int ct = 0; ct < 4; ++ct) acc[rt][ct] = zero4;

  bf16x8 aP[4], bP[4], aN[4], bN[4];
#pragma unroll
  for (int rt = 0; rt < 4; ++rt)
    aP[rt] = *(const bf16x8*)&x_lds[(rt * 16 + l15) * XSTR + ((lq * 8) ^ swz)];
#pragma unroll
  for (int ct = 0; ct < 4; ++ct)
    bP[ct] = *(const bf16x8*)&wqkvT[(((col0 >> 4) + ct) * 32 + lq) * 128 + l15 * 8];
#pragma unroll
  for (int kk = 0; kk < 8; ++kk) {
    if (kk < 7) {
      const int ko = ((kk + 1) * 32 + lq * 8) ^ swz;
#pragma unroll
      for (int rt = 0; rt < 4; ++rt)
        aN[rt] = *(const bf16x8*)&x_lds[(rt * 16 + l15) * XSTR + ko];
#pragma unroll
      for (int ct = 0; ct < 4; ++ct)
        bN[ct] = *(const bf16x8*)&wqkvT[((((col0 >> 4) + ct) * 8 + kk + 1) * 4 + lq) * 128 + l15 * 8];
    }
#pragma unroll
    for (int rt = 0; rt < 4; ++rt)
#pragma unroll
      for (int ct = 0; ct < 4; ++ct)
        acc[rt][ct] = SWAP ? mfma16(bP[ct], aP[rt], acc[rt][ct])
                           : mfma16(aP[rt], bP[ct], acc[rt][ct]);
#pragma unroll
    for (int rt = 0; rt < 4; ++rt) aP[rt] = aN[rt];
#pragma unroll
    for (int ct = 0; ct < 4; ++ct) bP[ct] = bN[ct];
  }
}

__global__ __launch_bounds__(256, 2)
void winattn_kernel(const float* __restrict__ x,
                    const unsigned short* __restrict__ wqkvT,
                    const unsigned short* __restrict__ woutT,
                    const float* __restrict__ bias64,
                    const float* __restrict__ b_out,
                    float* __restrict__ out) {
  __shared__ unsigned short smem[SMEM_ELTS];

  const int tid = threadIdx.x;
  const int lane = tid & 63;
  const int w = tid >> 6;
  const int l15 = lane & 15;
  const int lq = lane >> 4;
  const int swz = (l15 & 7) << 3;    // XOR bank swizzle key (row-determined)

  const int bid = blockIdx.x;
  const int win = bid & 255;
  const int img = bid >> 8;
  const int wy = win >> 4, wx = win & 15;

  unsigned short* x_lds  = smem + OFF_A;   // x, later overwritten by vT
  unsigned short* vT_lds = smem + OFF_A;
  unsigned short* qk_lds = smem + OFF_B;   // q round-trip, then k
  unsigned short* sc = smem + OFF_SC + w * (16 * SSTR);

  const f32x4 zero4 = {0.f, 0.f, 0.f, 0.f};
  const size_t img_base = (size_t)img * 128 * 128 * 256;

  // ---------- phase 1: stage x window -> bf16 LDS (coalesced, swizzled) ----------
  {
#pragma unroll
    for (int r = 0; r < 16; ++r) {
      int p = r * 4 + w;                 // pixel 0..63
      const float* src = x + img_base +
          (((size_t)(wy * 8 + (p >> 3)) * 128) + (wx * 8 + (p & 7))) * 256 + lane * 4;
      float4 v4 = *(const float4*)src;
      *(uint2*)&x_lds[p * XSTR + ((lane * 4) ^ ((p & 7) << 3))] =
          pack4(v4.x, v4.y, v4.z, v4.w);
    }
  }
  __syncthreads();   // bar1

  // ---------- phase 2a: Q chunk (cols w*64..+64), swapped -> packed store ----------
  {
    f32x4 acc[4][4];
    qkv_gemm<true>(acc, x_lds, wqkvT, w * 64, l15, lq, swz);
    // C-frag: (feat = ct*16+lq*4+r, pixel = rt*16+l15) -> b64 row-major store
#pragma unroll
    for (int rt = 0; rt < 4; ++rt)
#pragma unroll
      for (int ct = 0; ct < 4; ++ct)
        *(uint2*)&qk_lds[(rt * 16 + l15) * XSTR + ((w * 64 + ct * 16 + lq * 4) ^ swz)] =
            pack4(acc[rt][ct][0], acc[rt][ct][1], acc[rt][ct][2], acc[rt][ct][3]);
  }
  __syncthreads();   // bar2

  // q A-frags for this wave's 16 rows
  bf16x8 qf[8];
#pragma unroll
  for (int h = 0; h < 8; ++h)
    qf[h] = *(const bf16x8*)&qk_lds[(w * 16 + l15) * XSTR + ((h * 32 + lq * 8) ^ swz)];

  // ---------- phase 2b: K chunk (registers -> barrier -> packed LDS) ----------
  {
    f32x4 kacc[4][4];
    qkv_gemm<true>(kacc, x_lds, wqkvT, 256 + w * 64, l15, lq, swz);
    __syncthreads();   // bar3: all qf reads done -> safe to overwrite B
#pragma unroll
    for (int rt = 0; rt < 4; ++rt)
#pragma unroll
      for (int ct = 0; ct < 4; ++ct)
        *(uint2*)&qk_lds[(rt * 16 + l15) * XSTR + ((w * 64 + ct * 16 + lq * 4) ^ swz)] =
            pack4(kacc[rt][ct][0], kacc[rt][ct][1], kacc[rt][ct][2], kacc[rt][ct][3]);
  }

  // ---------- phase 2c: V chunk (normal orientation -> packed vT store) ----------
  {
    f32x4 vacc[4][4];
    qkv_gemm<false>(vacc, x_lds, wqkvT, 512 + w * 64, l15, lq, swz);
    __syncthreads();   // bar4: all x reads (region A) done -> safe to overwrite
    // C-frag: (pixel = rt*16+lq*4+r, feat = w*64+ct*16+l15) -> vT[feat][pixel]
#pragma unroll
    for (int rt = 0; rt < 4; ++rt)
#pragma unroll
      for (int ct = 0; ct < 4; ++ct)
        *(uint2*)&vT_lds[(w * 64 + ct * 16 + l15) * VSTR + ((rt * 16 + lq * 4) ^ swz)] =
            pack4(vacc[rt][ct][0], vacc[rt][ct][1], vacc[rt][ct][2], vacc[rt][ct][3]);
  }
  __syncthreads();   // bar5

  // bias, vectorized: S^T lane holds (i = w*16 + l15, j = rt*16+lq*4+r)
  // -> float4 over r along the j axis.  (r6 bug: missing w*16 here.)
  f32x4 bias4[4];
#pragma unroll
  for (int rt = 0; rt < 4; ++rt)
    bias4[rt] = *(const f32x4*)&bias64[(w * 16 + l15) * 64 + rt * 16 + lq * 4];

  // ---------- phase 3: attention + fused out-proj (wave rows w*16..+16) ----------
  const short one_bf = (short)0x3F80;            // bf16 1.0
  const bf16x8 ones = {one_bf, one_bf, one_bf, one_bf,
                       one_bf, one_bf, one_bf, one_bf};

  f32x4 ACC[16];
#pragma unroll
  for (int ct = 0; ct < 16; ++ct) ACC[ct] = zero4;

  // prologue: S^T(0) = mfma(k, q) -> exp
  f32x4 s_t[4];
#pragma unroll
  for (int rt = 0; rt < 4; ++rt) {
    const bf16x8 bk = *(const bf16x8*)&qk_lds[(rt * 16 + l15) * XSTR + ((lq * 8) ^ swz)];
    f32x4 t = mfma16(bk, qf[0], zero4);
#pragma unroll
    for (int r = 0; r < 4; ++r)
      s_t[rt][r] = __builtin_amdgcn_exp2f(t[r] * EXPSCALE + bias4[rt][r]);
  }

#pragma unroll
  for (int h = 0; h < 8; ++h) {
    // 1. P(h) -> scratch, packed b64 (P[i=l15][j]: j = rt*16+lq*4+r)
#pragma unroll
    for (int rt = 0; rt < 4; ++rt)
      *(uint2*)&sc[l15 * SSTR + ((rt * 16 + lq * 4) ^ swz)] =
          pack4(s_t[rt][0], s_t[rt][1], s_t[rt][2], s_t[rt][3]);

    // 2. S^T(h+1) + exp while the P write lands
    f32x4 sn[4];
    if (h < 7) {
#pragma unroll
      for (int rt = 0; rt < 4; ++rt) {
        const bf16x8 bk = *(const bf16x8*)&qk_lds[(rt * 16 + l15) * XSTR + (((h + 1) * 32 + lq * 8) ^ swz)];
        f32x4 t = mfma16(bk, qf[h + 1], zero4);
#pragma unroll
        for (int r = 0; r < 4; ++r)
          sn[rt][r] = __builtin_amdgcn_exp2f(t[r] * EXPSCALE + bias4[rt][r]);
      }
    }

    // 3. P A/B-frag readback (b128) + woutT prefetch
    const bf16x8 ap0 = *(const bf16x8*)&sc[l15 * SSTR + ((lq * 8) ^ swz)];
    const bf16x8 ap1 = *(const bf16x8*)&sc[l15 * SSTR + ((32 + lq * 8) ^ swz)];
    bf16x8 bw[16];
#pragma unroll
    for (int ct = 0; ct < 16; ++ct)
      bw[ct] = *(const bf16x8*)&woutT[((ct * 8 + h) * 4 + lq) * 128 + l15 * 8];

    // 4. PV swapped: oh^T = mfma(vT, P^T); osum^T = mfma(ones, P^T)
    f32x4 o0 = zero4, o1 = zero4, osum = zero4;
    {
      const bf16x8 bv00 = *(const bf16x8*)&vT_lds[(h * 32 + l15) * VSTR + ((lq * 8) ^ swz)];
      const bf16x8 bv01 = *(const bf16x8*)&vT_lds[(h * 32 + l15) * VSTR + ((32 + lq * 8) ^ swz)];
      const bf16x8 bv10 = *(const bf16x8*)&vT_lds[(h * 32 + 16 + l15) * VSTR + ((lq * 8) ^ swz)];
      const bf16x8 bv11 = *(const bf16x8*)&vT_lds[(h * 32 + 16 + l15) * VSTR + ((32 + lq * 8) ^ swz)];
      o0 = mfma16(bv00, ap0, o0);  o0 = mfma16(bv01, ap1, o0);
      o1 = mfma16(bv10, ap0, o1);  o1 = mfma16(bv11, ap1, o1);
      osum = mfma16(ones, ap0, osum);
      osum = mfma16(ones, ap1, osum);
    }

    // 5. normalize (rsum replicated at i=l15 in every osum reg) -> packed oh
    const float rinv = __builtin_amdgcn_rcpf(osum[0]);
    *(uint2*)&sc[l15 * SSTR + ((lq * 4) ^ swz)] =
        pack4(o0[0] * rinv, o0[1] * rinv, o0[2] * rinv, o0[3] * rinv);
    *(uint2*)&sc[l15 * SSTR + ((16 + lq * 4) ^ swz)] =
        pack4(o1[0] * rinv, o1[1] * rinv, o1[2] * rinv, o1[3] * rinv);

    // 6. out-proj slice: ACC(16x256) += oh(16x32) @ w_out[h*32.., :]
    const bf16x8 ao = *(const bf16x8*)&sc[l15 * SSTR + ((lq * 8) ^ swz)];
#pragma unroll
    for (int ct = 0; ct < 16; ++ct)
      ACC[ct] = mfma16(ao, bw[ct], ACC[ct]);

    // 7. shift pipeline
    if (h < 7) {
#pragma unroll
      for (int rt = 0; rt < 4; ++rt) s_t[rt] = sn[rt];
    }
  }

  // ---------- phase 4: epilogue ----------
  {
#pragma unroll
    for (int ct = 0; ct < 16; ++ct) {
      const int n = ct * 16 + l15;
      const float bo = b_out[n];
#pragma unroll
      for (int r = 0; r < 4; ++r) {
        const int p = w * 16 + lq * 4 + r;
        const size_t off = img_base +
            (((size_t)(wy * 8 + (p >> 3)) * 128) + (wx * 8 + (p & 7))) * 256 + n;
        out[off] = ACC[ct][r] + bo;
      }
    }
  }
}

extern "C" void kernel_launch(void* const* d_in, const int* in_sizes, int n_in,
                              void* d_out, int out_size, void* d_ws, size_t ws_size,
                              hipStream_t stream) {
  const float* x       = (const float*)d_in[0];
  const float* w_qkv   = (const float*)d_in[1];
  const float* pos_emb = (const float*)d_in[2];
  const float* w_out   = (const float*)d_in[3];
  const float* b_out   = (const float*)d_in[4];
  float* out = (float*)d_out;

  unsigned short* wqkvT = (unsigned short*)d_ws;
  unsigned short* woutT = wqkvT + 768 * 256;
  float* bias64 = (float*)(woutT + 256 * 256);

  prep_kernel<<<96, 256, 0, stream>>>(w_qkv, w_out, pos_emb, wqkvT, woutT, bias64);
  winattn_kernel<<<2048, 256, 0, stream>>>(x, wqkvT, woutT, bias64, b_out, out);
}

// Round 8
// 132.404 us; speedup vs baseline: 1.0743x; 1.0743x over previous
//
#include <hip/hip_runtime.h>
#include <hip/hip_bf16.h>

// Fused Swin window attention for MI355X (gfx950) — round 8.
// One block per 8x8 window (2048 blocks x 256 threads, 4 waves), 2 blocks/CU.
// r7 lesson: padded LDS strides (264/72 elem = odd multiple of 16B) ALREADY
// rotate row bank phases -> natural layout is at the b128 bank floor. The
// added XOR swizzle re-aligned lanes (bank = t + (c^t) collapses for c=3)
// -> 44.4M conflict cycles. r8 drops the swizzle, keeps everything else:
//   * swapped-MFMA orientations -> all LDS stores packed b64 (no scalar u16).
//   * out-proj ALSO swapped (mfma(w_out, oh)) -> epilogue = 16 float4 stores.
//   * software-pipelined QKV GEMM + head loop (from r5).
// LDS footprint: 79,872 B -> 2 blocks/CU.

typedef __attribute__((ext_vector_type(8))) short bf16x8;
typedef __attribute__((ext_vector_type(4))) float f32x4;

__device__ __forceinline__ f32x4 mfma16(bf16x8 a, bf16x8 b, f32x4 c) {
  return __builtin_amdgcn_mfma_f32_16x16x32_bf16(a, b, c, 0, 0, 0);
}

__device__ __forceinline__ unsigned short f2bf(float f) {
  __hip_bfloat16 h = __float2bfloat16(f);
  return *reinterpret_cast<unsigned short*>(&h);
}

__device__ __forceinline__ uint2 pack4(float a, float b, float c, float d) {
  union { unsigned short u[4]; uint2 v; } pk;
  pk.u[0] = f2bf(a); pk.u[1] = f2bf(b); pk.u[2] = f2bf(c); pk.u[3] = f2bf(d);
  return pk.v;
}

#define LOG2E 1.4426950408889634f
#define EXPSCALE (0.17677669529663687f * 1.4426950408889634f)

// LDS layout (ushort elements); strides are odd multiples of 8 elem (16B)
#define XSTR 264     // x / q / k row stride (64 rows)
#define VSTR 72      // vT row stride (256 rows)
#define SSTR 72      // per-wave scratch row stride (16 rows)
#define OFF_A  0     // region A: x (64x264) then vT (256x72=18432)
#define OFF_B  18432 // region B: q then k (64x264=16896)
#define OFF_SC 35328 // scratch: 4 waves x 16 x 72 = 4608
#define SMEM_ELTS 39936  // 79,872 bytes -> 2 blocks/CU

// Weight tiled layout: elem(n,k) -> ((((n>>4)*8+(k>>5))*4+((k>>3)&3))*16+(n&15))*8+(k&7)
__global__ void prep_kernel(const float* __restrict__ w_qkv,
                            const float* __restrict__ w_out,
                            const float* __restrict__ pos_emb,
                            unsigned short* __restrict__ wqkvT,
                            unsigned short* __restrict__ woutT,
                            float* __restrict__ bias64) {
  const int stride = gridDim.x * blockDim.x;
  const int tid = blockIdx.x * blockDim.x + threadIdx.x;
  for (int i = tid; i < 768 * 256; i += stride) {
    int n = i >> 8, k = i & 255;
    int off = ((((n >> 4) * 8 + (k >> 5)) * 4 + ((k >> 3) & 3)) * 16 + (n & 15)) * 8 + (k & 7);
    wqkvT[off] = f2bf(w_qkv[k * 768 + n]);
  }
  for (int i = tid; i < 256 * 256; i += stride) {
    int n = i >> 8, k = i & 255;
    int off = ((((n >> 4) * 8 + (k >> 5)) * 4 + ((k >> 3) & 3)) * 16 + (n & 15)) * 8 + (k & 7);
    woutT[off] = f2bf(w_out[k * 256 + n]);
  }
  for (int i = tid; i < 64 * 64; i += stride) {
    int a = i >> 6, b = i & 63;
    int d0 = (b >> 3) - (a >> 3) + 7;
    int d1 = (b & 7) - (a & 7) + 7;
    bias64[i] = pos_emb[d0 * 15 + d1] * LOG2E;   // pre-scaled for exp2
  }
}

// QKV GEMM, software-pipelined k-steps. SWAP=true computes the transposed
// tile (A=weight frag, B=x frag) so the C-frag row axis = output feature.
template <bool SWAP>
__device__ __forceinline__ void qkv_gemm(f32x4 (&acc)[4][4],
                                         const unsigned short* __restrict__ x_lds,
                                         const unsigned short* __restrict__ wqkvT,
                                         int col0, int l15, int lq) {
  const f32x4 zero4 = {0.f, 0.f, 0.f, 0.f};
#pragma unroll
  for (int rt = 0; rt < 4; ++rt)
#pragma unroll
    for (int ct = 0; ct < 4; ++ct) acc[rt][ct] = zero4;

  bf16x8 aP[4], bP[4], aN[4], bN[4];
#pragma unroll
  for (int rt = 0; rt < 4; ++rt)
    aP[rt] = *(const bf16x8*)&x_lds[(rt * 16 + l15) * XSTR + lq * 8];
#pragma unroll
  for (int ct = 0; ct < 4; ++ct)
    bP[ct] = *(const bf16x8*)&wqkvT[(((col0 >> 4) + ct) * 32 + lq) * 128 + l15 * 8];
#pragma unroll
  for (int kk = 0; kk < 8; ++kk) {
    if (kk < 7) {
      const int ko = (kk + 1) * 32 + lq * 8;
#pragma unroll
      for (int rt = 0; rt < 4; ++rt)
        aN[rt] = *(const bf16x8*)&x_lds[(rt * 16 + l15) * XSTR + ko];
#pragma unroll
      for (int ct = 0; ct < 4; ++ct)
        bN[ct] = *(const bf16x8*)&wqkvT[((((col0 >> 4) + ct) * 8 + kk + 1) * 4 + lq) * 128 + l15 * 8];
    }
#pragma unroll
    for (int rt = 0; rt < 4; ++rt)
#pragma unroll
      for (int ct = 0; ct < 4; ++ct)
        acc[rt][ct] = SWAP ? mfma16(bP[ct], aP[rt], acc[rt][ct])
                           : mfma16(aP[rt], bP[ct], acc[rt][ct]);
#pragma unroll
    for (int rt = 0; rt < 4; ++rt) aP[rt] = aN[rt];
#pragma unroll
    for (int ct = 0; ct < 4; ++ct) bP[ct] = bN[ct];
  }
}

__global__ __launch_bounds__(256, 2)
void winattn_kernel(const float* __restrict__ x,
                    const unsigned short* __restrict__ wqkvT,
                    const unsigned short* __restrict__ woutT,
                    const float* __restrict__ bias64,
                    const float* __restrict__ b_out,
                    float* __restrict__ out) {
  __shared__ unsigned short smem[SMEM_ELTS];

  const int tid = threadIdx.x;
  const int lane = tid & 63;
  const int w = tid >> 6;
  const int l15 = lane & 15;
  const int lq = lane >> 4;

  const int bid = blockIdx.x;
  const int win = bid & 255;
  const int img = bid >> 8;
  const int wy = win >> 4, wx = win & 15;

  unsigned short* x_lds  = smem + OFF_A;   // x, later overwritten by vT
  unsigned short* vT_lds = smem + OFF_A;
  unsigned short* qk_lds = smem + OFF_B;   // q round-trip, then k
  unsigned short* sc = smem + OFF_SC + w * (16 * SSTR);

  const f32x4 zero4 = {0.f, 0.f, 0.f, 0.f};
  const size_t img_base = (size_t)img * 128 * 128 * 256;

  // ---------- phase 1: stage x window -> bf16 LDS (coalesced) ----------
  {
#pragma unroll
    for (int r = 0; r < 16; ++r) {
      int p = r * 4 + w;                 // pixel 0..63
      const float* src = x + img_base +
          (((size_t)(wy * 8 + (p >> 3)) * 128) + (wx * 8 + (p & 7))) * 256 + lane * 4;
      float4 v4 = *(const float4*)src;
      *(uint2*)&x_lds[p * XSTR + lane * 4] = pack4(v4.x, v4.y, v4.z, v4.w);
    }
  }
  __syncthreads();   // bar1

  // ---------- phase 2a: Q chunk (cols w*64..+64), swapped -> packed store ----------
  {
    f32x4 acc[4][4];
    qkv_gemm<true>(acc, x_lds, wqkvT, w * 64, l15, lq);
    // C-frag: (feat = ct*16+lq*4+r, pixel = rt*16+l15) -> b64 row-major store
#pragma unroll
    for (int rt = 0; rt < 4; ++rt)
#pragma unroll
      for (int ct = 0; ct < 4; ++ct)
        *(uint2*)&qk_lds[(rt * 16 + l15) * XSTR + w * 64 + ct * 16 + lq * 4] =
            pack4(acc[rt][ct][0], acc[rt][ct][1], acc[rt][ct][2], acc[rt][ct][3]);
  }
  __syncthreads();   // bar2

  // q A-frags for this wave's 16 rows
  bf16x8 qf[8];
#pragma unroll
  for (int h = 0; h < 8; ++h)
    qf[h] = *(const bf16x8*)&qk_lds[(w * 16 + l15) * XSTR + h * 32 + lq * 8];

  // ---------- phase 2b: K chunk (registers -> barrier -> packed LDS) ----------
  {
    f32x4 kacc[4][4];
    qkv_gemm<true>(kacc, x_lds, wqkvT, 256 + w * 64, l15, lq);
    __syncthreads();   // bar3: all qf reads done -> safe to overwrite B
#pragma unroll
    for (int rt = 0; rt < 4; ++rt)
#pragma unroll
      for (int ct = 0; ct < 4; ++ct)
        *(uint2*)&qk_lds[(rt * 16 + l15) * XSTR + w * 64 + ct * 16 + lq * 4] =
            pack4(kacc[rt][ct][0], kacc[rt][ct][1], kacc[rt][ct][2], kacc[rt][ct][3]);
  }

  // ---------- phase 2c: V chunk (normal orientation -> packed vT store) ----------
  {
    f32x4 vacc[4][4];
    qkv_gemm<false>(vacc, x_lds, wqkvT, 512 + w * 64, l15, lq);
    __syncthreads();   // bar4: all x reads (region A) done -> safe to overwrite
    // C-frag: (pixel = rt*16+lq*4+r, feat = w*64+ct*16+l15) -> vT[feat][pixel]
#pragma unroll
    for (int rt = 0; rt < 4; ++rt)
#pragma unroll
      for (int ct = 0; ct < 4; ++ct)
        *(uint2*)&vT_lds[(w * 64 + ct * 16 + l15) * VSTR + rt * 16 + lq * 4] =
            pack4(vacc[rt][ct][0], vacc[rt][ct][1], vacc[rt][ct][2], vacc[rt][ct][3]);
  }
  __syncthreads();   // bar5

  // bias: S^T lane holds (i = w*16 + l15, j = rt*16+lq*4+r) -> float4 over r
  f32x4 bias4[4];
#pragma unroll
  for (int rt = 0; rt < 4; ++rt)
    bias4[rt] = *(const f32x4*)&bias64[(w * 16 + l15) * 64 + rt * 16 + lq * 4];

  // ---------- phase 3: attention + fused out-proj (wave rows w*16..+16) ----------
  const short one_bf = (short)0x3F80;            // bf16 1.0
  const bf16x8 ones = {one_bf, one_bf, one_bf, one_bf,
                       one_bf, one_bf, one_bf, one_bf};

  f32x4 ACC[16];
#pragma unroll
  for (int ct = 0; ct < 16; ++ct) ACC[ct] = zero4;

  // prologue: S^T(0) = mfma(k, q) -> exp
  f32x4 s_t[4];
#pragma unroll
  for (int rt = 0; rt < 4; ++rt) {
    const bf16x8 bk = *(const bf16x8*)&qk_lds[(rt * 16 + l15) * XSTR + lq * 8];
    f32x4 t = mfma16(bk, qf[0], zero4);
#pragma unroll
    for (int r = 0; r < 4; ++r)
      s_t[rt][r] = __builtin_amdgcn_exp2f(t[r] * EXPSCALE + bias4[rt][r]);
  }

#pragma unroll
  for (int h = 0; h < 8; ++h) {
    // 1. P(h) -> scratch, packed b64 (P[i=l15][j]: j = rt*16+lq*4+r)
#pragma unroll
    for (int rt = 0; rt < 4; ++rt)
      *(uint2*)&sc[l15 * SSTR + rt * 16 + lq * 4] =
          pack4(s_t[rt][0], s_t[rt][1], s_t[rt][2], s_t[rt][3]);

    // 2. S^T(h+1) + exp while the P write lands
    f32x4 sn[4];
    if (h < 7) {
#pragma unroll
      for (int rt = 0; rt < 4; ++rt) {
        const bf16x8 bk = *(const bf16x8*)&qk_lds[(rt * 16 + l15) * XSTR + (h + 1) * 32 + lq * 8];
        f32x4 t = mfma16(bk, qf[h + 1], zero4);
#pragma unroll
        for (int r = 0; r < 4; ++r)
          sn[rt][r] = __builtin_amdgcn_exp2f(t[r] * EXPSCALE + bias4[rt][r]);
      }
    }

    // 3. P A/B-frag readback (b128) + woutT prefetch
    const bf16x8 ap0 = *(const bf16x8*)&sc[l15 * SSTR + lq * 8];
    const bf16x8 ap1 = *(const bf16x8*)&sc[l15 * SSTR + 32 + lq * 8];
    bf16x8 bw[16];
#pragma unroll
    for (int ct = 0; ct < 16; ++ct)
      bw[ct] = *(const bf16x8*)&woutT[((ct * 8 + h) * 4 + lq) * 128 + l15 * 8];

    // 4. PV swapped: oh^T = mfma(vT, P^T); osum^T = mfma(ones, P^T)
    f32x4 o0 = zero4, o1 = zero4, osum = zero4;
    {
      const bf16x8 bv00 = *(const bf16x8*)&vT_lds[(h * 32 + l15) * VSTR + lq * 8];
      const bf16x8 bv01 = *(const bf16x8*)&vT_lds[(h * 32 + l15) * VSTR + 32 + lq * 8];
      const bf16x8 bv10 = *(const bf16x8*)&vT_lds[(h * 32 + 16 + l15) * VSTR + lq * 8];
      const bf16x8 bv11 = *(const bf16x8*)&vT_lds[(h * 32 + 16 + l15) * VSTR + 32 + lq * 8];
      o0 = mfma16(bv00, ap0, o0);  o0 = mfma16(bv01, ap1, o0);
      o1 = mfma16(bv10, ap0, o1);  o1 = mfma16(bv11, ap1, o1);
      osum = mfma16(ones, ap0, osum);
      osum = mfma16(ones, ap1, osum);
    }

    // 5. normalize (rsum replicated at col=l15 in every osum reg) -> packed oh
    const float rinv = __builtin_amdgcn_rcpf(osum[0]);
    *(uint2*)&sc[l15 * SSTR + lq * 4] =
        pack4(o0[0] * rinv, o0[1] * rinv, o0[2] * rinv, o0[3] * rinv);
    *(uint2*)&sc[l15 * SSTR + 16 + lq * 4] =
        pack4(o1[0] * rinv, o1[1] * rinv, o1[2] * rinv, o1[3] * rinv);

    // 6. out-proj slice, swapped: ACC = mfma(w_out, oh) -> D row = feature
    const bf16x8 ao = *(const bf16x8*)&sc[l15 * SSTR + lq * 8];
#pragma unroll
    for (int ct = 0; ct < 16; ++ct)
      ACC[ct] = mfma16(bw[ct], ao, ACC[ct]);

    // 7. shift pipeline
    if (h < 7) {
#pragma unroll
      for (int rt = 0; rt < 4; ++rt) s_t[rt] = sn[rt];
    }
  }

  // ---------- phase 4: epilogue (float4 stores; ACC col = pixel l15) ----------
  {
    const int p = w * 16 + l15;   // this lane's pixel
    float* orow = out + img_base +
        (((size_t)(wy * 8 + (p >> 3)) * 128) + (wx * 8 + (p & 7))) * 256;
#pragma unroll
    for (int ct = 0; ct < 16; ++ct) {
      const int n0 = ct * 16 + lq * 4;
      const f32x4 bo4 = *(const f32x4*)&b_out[n0];
      f32x4 st;
#pragma unroll
      for (int r = 0; r < 4; ++r) st[r] = ACC[ct][r] + bo4[r];
      *(f32x4*)(orow + n0) = st;
    }
  }
}

extern "C" void kernel_launch(void* const* d_in, const int* in_sizes, int n_in,
                              void* d_out, int out_size, void* d_ws, size_t ws_size,
                              hipStream_t stream) {
  const float* x       = (const float*)d_in[0];
  const float* w_qkv   = (const float*)d_in[1];
  const float* pos_emb = (const float*)d_in[2];
  const float* w_out   = (const float*)d_in[3];
  const float* b_out   = (const float*)d_in[4];
  float* out = (float*)d_out;

  unsigned short* wqkvT = (unsigned short*)d_ws;
  unsigned short* woutT = wqkvT + 768 * 256;
  float* bias64 = (float*)(woutT + 256 * 256);

  prep_kernel<<<96, 256, 0, stream>>>(w_qkv, w_out, pos_emb, wqkvT, woutT, bias64);
  winattn_kernel<<<2048, 256, 0, stream>>>(x, wqkvT, woutT, bias64, b_out, out);
}

// Round 9
// 116.525 us; speedup vs baseline: 1.2207x; 1.1363x over previous
//
#include <hip/hip_runtime.h>
#include <hip/hip_bf16.h>

// Fused Swin window attention for MI355X (gfx950) — round 9: head-partition.
// r8 was latency-bound at 2 waves/SIMD: pixel-partitioned attention forces
// k (64x256) + vT (256x64) to be block-shared in LDS = 64KB irreducible ->
// 2 blocks/CU cap. r9 re-partitions phase 3 BY HEAD: wave w runs heads
// {2w,2w+1} (exactly the q/k/v columns it computed in phase 2) over all 64
// pixels -> k,v,q live in the producing wave's REGISTERS (96 VGPR), nothing
// shared except x staging (33.8KB, overlaid by oh staging in phase 3) and a
// 2.5KB/wave round-trip scratch. LDS 79.9 -> 44.0 KB -> 3 blocks/CU.
//   * barriers 5 -> 3 (all q/k/v round-trips are wave-local).
//   * out-proj restructured to ONE K=256 GEMM from staged oh (woutT frags
//     fetched 32x instead of 128x; same MFMA count).
//   * softmax row-sum: kv axis spans lq lanes -> 15 adds + 2 shfl_xor + rcp
//     (replaces the 2 osum MFMAs).
//   * NO explicit phase-2 pipelining: VGPR headroom for 3 waves/SIMD (<=168);
//     12 waves/CU TLP hides the load latency instead.
// All LDS round-trips reuse r8's verified C-frag<->A-frag index patterns.

typedef __attribute__((ext_vector_type(8))) short bf16x8;
typedef __attribute__((ext_vector_type(4))) float f32x4;

__device__ __forceinline__ f32x4 mfma16(bf16x8 a, bf16x8 b, f32x4 c) {
  return __builtin_amdgcn_mfma_f32_16x16x32_bf16(a, b, c, 0, 0, 0);
}

__device__ __forceinline__ unsigned short f2bf(float f) {
  __hip_bfloat16 h = __float2bfloat16(f);
  return *reinterpret_cast<unsigned short*>(&h);
}

__device__ __forceinline__ uint2 pack4(float a, float b, float c, float d) {
  union { unsigned short u[4]; uint2 v; } pk;
  pk.u[0] = f2bf(a); pk.u[1] = f2bf(b); pk.u[2] = f2bf(c); pk.u[3] = f2bf(d);
  return pk.v;
}

#define LOG2E 1.4426950408889634f
#define EXPSCALE (0.17677669529663687f * 1.4426950408889634f)

// LDS layout (ushort elements); row strides multiples of 8 elem (16B) for b128.
#define XO  264           // x / oh region row stride (64 rows)
#define RTS 40            // per-wave RT scratch row stride (32 rows used)
#define PS  72            // P scratch row stride (16 rows)
#define RT_ELEMS 1280     // per-wave scratch: 32x40 (covers P's 16x72=1152)
#define OFF_RT 16896      // 64*264
#define SMEM_ELTS 22016   // 16896 + 4*1280 = 44,032 B -> 3 blocks/CU

// Weight tiled layout: elem(n,k) -> ((((n>>4)*8+(k>>5))*4+((k>>3)&3))*16+(n&15))*8+(k&7)
__global__ void prep_kernel(const float* __restrict__ w_qkv,
                            const float* __restrict__ w_out,
                            const float* __restrict__ pos_emb,
                            unsigned short* __restrict__ wqkvT,
                            unsigned short* __restrict__ woutT,
                            float* __restrict__ bias64) {
  const int stride = gridDim.x * blockDim.x;
  const int tid = blockIdx.x * blockDim.x + threadIdx.x;
  for (int i = tid; i < 768 * 256; i += stride) {
    int n = i >> 8, k = i & 255;
    int off = ((((n >> 4) * 8 + (k >> 5)) * 4 + ((k >> 3) & 3)) * 16 + (n & 15)) * 8 + (k & 7);
    wqkvT[off] = f2bf(w_qkv[k * 768 + n]);
  }
  for (int i = tid; i < 256 * 256; i += stride) {
    int n = i >> 8, k = i & 255;
    int off = ((((n >> 4) * 8 + (k >> 5)) * 4 + ((k >> 3) & 3)) * 16 + (n & 15)) * 8 + (k & 7);
    woutT[off] = f2bf(w_out[k * 256 + n]);
  }
  for (int i = tid; i < 64 * 64; i += stride) {
    int a = i >> 6, b = i & 63;
    int d0 = (b >> 3) - (a >> 3) + 7;
    int d1 = (b & 7) - (a & 7) + 7;
    bias64[i] = pos_emb[d0 * 15 + d1] * LOG2E;   // pre-scaled for exp2
  }
}

// 64px x 32col GEMM slice. SWAP=true: acc = mfma(w, x) -> (feat row, px col).
// SWAP=false: acc = mfma(x, w) -> (px row, feat col). No explicit pipelining.
template <bool SWAP>
__device__ __forceinline__ void gemm32(f32x4 (&acc)[4][2],
                                       const unsigned short* __restrict__ a_lds,
                                       const unsigned short* __restrict__ wT,
                                       int col0, int l15, int lq) {
  const f32x4 zero4 = {0.f, 0.f, 0.f, 0.f};
#pragma unroll
  for (int rt = 0; rt < 4; ++rt)
#pragma unroll
    for (int ct = 0; ct < 2; ++ct) acc[rt][ct] = zero4;
#pragma unroll
  for (int kk = 0; kk < 8; ++kk) {
    bf16x8 a[4], b[2];
#pragma unroll
    for (int rt = 0; rt < 4; ++rt)
      a[rt] = *(const bf16x8*)&a_lds[(rt * 16 + l15) * XO + kk * 32 + lq * 8];
#pragma unroll
    for (int ct = 0; ct < 2; ++ct)
      b[ct] = *(const bf16x8*)&wT[((((col0 >> 4) + ct) * 8 + kk) * 4 + lq) * 128 + l15 * 8];
#pragma unroll
    for (int rt = 0; rt < 4; ++rt)
#pragma unroll
      for (int ct = 0; ct < 2; ++ct)
        acc[rt][ct] = SWAP ? mfma16(b[ct], a[rt], acc[rt][ct])
                           : mfma16(a[rt], b[ct], acc[rt][ct]);
  }
}

__global__ __launch_bounds__(256, 3)
void winattn_kernel(const float* __restrict__ x,
                    const unsigned short* __restrict__ wqkvT,
                    const unsigned short* __restrict__ woutT,
                    const float* __restrict__ bias64,
                    const float* __restrict__ b_out,
                    float* __restrict__ out) {
  __shared__ unsigned short smem[SMEM_ELTS];

  const int tid = threadIdx.x;
  const int lane = tid & 63;
  const int w = tid >> 6;
  const int l15 = lane & 15;
  const int lq = lane >> 4;

  const int bid = blockIdx.x;
  const int win = bid & 255;
  const int img = bid >> 8;
  const int wy = win >> 4, wx = win & 15;

  unsigned short* x_lds  = smem;                 // phase 1-2: x; phase 3-4: oh
  unsigned short* oh_lds = smem;
  unsigned short* rt_buf = smem + OFF_RT + w * RT_ELEMS;   // wave-private

  const f32x4 zero4 = {0.f, 0.f, 0.f, 0.f};
  const size_t img_base = (size_t)img * 128 * 128 * 256;

  // ---------- phase 1: stage x window -> bf16 LDS (coalesced) ----------
  {
#pragma unroll
    for (int r = 0; r < 16; ++r) {
      int p = r * 4 + w;                 // pixel 0..63
      const float* src = x + img_base +
          (((size_t)(wy * 8 + (p >> 3)) * 128) + (wx * 8 + (p & 7))) * 256 + lane * 4;
      float4 v4 = *(const float4*)src;
      *(uint2*)&x_lds[p * XO + lane * 4] = pack4(v4.x, v4.y, v4.z, v4.w);
    }
  }
  __syncthreads();   // bar1

  // ---------- phase 2: q/k/v for this wave's 2 heads, all wave-local ----------
  // qf/kf[it][hh]: lane = (px it*16+l15, feat hh*32+lq*8..+8)  (A/B-frag)
  // vf[ft][kk][hh]: lane = (feat hh*32+ft*16+l15, kv px kk*32+lq*8..+8) (A-frag)
  bf16x8 qf[4][2], kf[4][2], vf[2][2][2];
  {
    f32x4 acc[4][2];
#pragma unroll
    for (int hh = 0; hh < 2; ++hh) {    // q chunk (swapped: feat rows, px cols)
      gemm32<true>(acc, x_lds, wqkvT, w * 64 + hh * 32, l15, lq);
#pragma unroll
      for (int h2 = 0; h2 < 2; ++h2) {  // px halves through RT scratch
#pragma unroll
        for (int rr = 0; rr < 2; ++rr)
#pragma unroll
          for (int ct = 0; ct < 2; ++ct)
            *(uint2*)&rt_buf[(rr * 16 + l15) * RTS + ct * 16 + lq * 4] =
                pack4(acc[h2 * 2 + rr][ct][0], acc[h2 * 2 + rr][ct][1],
                      acc[h2 * 2 + rr][ct][2], acc[h2 * 2 + rr][ct][3]);
#pragma unroll
        for (int rr = 0; rr < 2; ++rr)
          qf[h2 * 2 + rr][hh] = *(const bf16x8*)&rt_buf[(rr * 16 + l15) * RTS + lq * 8];
      }
    }
#pragma unroll
    for (int hh = 0; hh < 2; ++hh) {    // k chunk
      gemm32<true>(acc, x_lds, wqkvT, 256 + w * 64 + hh * 32, l15, lq);
#pragma unroll
      for (int h2 = 0; h2 < 2; ++h2) {
#pragma unroll
        for (int rr = 0; rr < 2; ++rr)
#pragma unroll
          for (int ct = 0; ct < 2; ++ct)
            *(uint2*)&rt_buf[(rr * 16 + l15) * RTS + ct * 16 + lq * 4] =
                pack4(acc[h2 * 2 + rr][ct][0], acc[h2 * 2 + rr][ct][1],
                      acc[h2 * 2 + rr][ct][2], acc[h2 * 2 + rr][ct][3]);
#pragma unroll
        for (int rr = 0; rr < 2; ++rr)
          kf[h2 * 2 + rr][hh] = *(const bf16x8*)&rt_buf[(rr * 16 + l15) * RTS + lq * 8];
      }
    }
#pragma unroll
    for (int hh = 0; hh < 2; ++hh) {    // v chunk (normal: px rows, feat cols)
      gemm32<false>(acc, x_lds, wqkvT, 512 + w * 64 + hh * 32, l15, lq);
#pragma unroll
      for (int h2 = 0; h2 < 2; ++h2) {  // kv-px halves; transpose via RT
#pragma unroll
        for (int rr = 0; rr < 2; ++rr)
#pragma unroll
          for (int ct = 0; ct < 2; ++ct)
            *(uint2*)&rt_buf[(ct * 16 + l15) * RTS + rr * 16 + lq * 4] =
                pack4(acc[h2 * 2 + rr][ct][0], acc[h2 * 2 + rr][ct][1],
                      acc[h2 * 2 + rr][ct][2], acc[h2 * 2 + rr][ct][3]);
#pragma unroll
        for (int ft = 0; ft < 2; ++ft)
          vf[ft][h2][hh] = *(const bf16x8*)&rt_buf[(ft * 16 + l15) * RTS + lq * 8];
      }
    }
  }
  __syncthreads();   // bar2: all x reads done -> oh region (overlays x) safe

  // ---------- phase 3: attention for heads {2w, 2w+1}, all 64 pixels ----------
#pragma unroll
  for (int it = 0; it < 4; ++it) {
    f32x4 bias4[4];
#pragma unroll
    for (int jt = 0; jt < 4; ++jt)
      bias4[jt] = *(const f32x4*)&bias64[(it * 16 + l15) * 64 + jt * 16 + lq * 4];
#pragma unroll
    for (int hh = 0; hh < 2; ++hh) {
      // S^T = mfma(k, q): D[kv jt*16+lq*4+r][q px it*16+l15]
      f32x4 s[4];
#pragma unroll
      for (int jt = 0; jt < 4; ++jt)
        s[jt] = mfma16(kf[jt][hh], qf[it][hh], zero4);
      // p = exp2(s*ES + bias); row-sum over kv (regs + lq lanes)
      float rs = 0.f;
#pragma unroll
      for (int jt = 0; jt < 4; ++jt)
#pragma unroll
        for (int r = 0; r < 4; ++r) {
          s[jt][r] = __builtin_amdgcn_exp2f(s[jt][r] * EXPSCALE + bias4[jt][r]);
          rs += s[jt][r];
        }
      rs += __shfl_xor(rs, 16);
      rs += __shfl_xor(rs, 32);
      const float rinv = __builtin_amdgcn_rcpf(rs);

      // P -> wave-private scratch (P[q l15][kv]), packed b64
#pragma unroll
      for (int jt = 0; jt < 4; ++jt)
        *(uint2*)&rt_buf[l15 * PS + jt * 16 + lq * 4] =
            pack4(s[jt][0], s[jt][1], s[jt][2], s[jt][3]);
      const bf16x8 ap0 = *(const bf16x8*)&rt_buf[l15 * PS + lq * 8];
      const bf16x8 ap1 = *(const bf16x8*)&rt_buf[l15 * PS + 32 + lq * 8];

      // oh^T = mfma(vT, P^T): D[feat ft*16+lq*4+r][q px it*16+l15]
      f32x4 o0 = mfma16(vf[0][0][hh], ap0, zero4);
      o0 = mfma16(vf[0][1][hh], ap1, o0);
      f32x4 o1 = mfma16(vf[1][0][hh], ap0, zero4);
      o1 = mfma16(vf[1][1][hh], ap1, o1);

      // normalize + stage oh (px-major shared region), packed b64
      *(uint2*)&oh_lds[(it * 16 + l15) * XO + w * 64 + hh * 32 + lq * 4] =
          pack4(o0[0] * rinv, o0[1] * rinv, o0[2] * rinv, o0[3] * rinv);
      *(uint2*)&oh_lds[(it * 16 + l15) * XO + w * 64 + hh * 32 + 16 + lq * 4] =
          pack4(o1[0] * rinv, o1[1] * rinv, o1[2] * rinv, o1[3] * rinv);
    }
  }
  __syncthreads();   // bar3: oh complete

  // ---------- phase 4: out-proj, one K=256 GEMM (swapped) + epilogue ----------
  {
    f32x4 ACC[4][4];
#pragma unroll
    for (int rt = 0; rt < 4; ++rt)
#pragma unroll
      for (int ct = 0; ct < 4; ++ct) ACC[rt][ct] = zero4;
#pragma unroll
    for (int kk = 0; kk < 8; ++kk) {
      bf16x8 a[4], b[4];
#pragma unroll
      for (int rt = 0; rt < 4; ++rt)
        a[rt] = *(const bf16x8*)&oh_lds[(rt * 16 + l15) * XO + kk * 32 + lq * 8];
#pragma unroll
      for (int ct = 0; ct < 4; ++ct)
        b[ct] = *(const bf16x8*)&woutT[(((w * 4 + ct) * 8 + kk) * 4 + lq) * 128 + l15 * 8];
#pragma unroll
      for (int rt = 0; rt < 4; ++rt)
#pragma unroll
        for (int ct = 0; ct < 4; ++ct)
          ACC[rt][ct] = mfma16(b[ct], a[rt], ACC[rt][ct]);   // D[ofeat][px]
    }
    // epilogue: D rows = ofeat w*64+ct*16+lq*4+r, cols = px rt*16+l15
#pragma unroll
    for (int rt = 0; rt < 4; ++rt) {
      const int p = rt * 16 + l15;
      float* orow = out + img_base +
          (((size_t)(wy * 8 + (p >> 3)) * 128) + (wx * 8 + (p & 7))) * 256;
#pragma unroll
      for (int ct = 0; ct < 4; ++ct) {
        const int n0 = w * 64 + ct * 16 + lq * 4;
        const f32x4 bo4 = *(const f32x4*)&b_out[n0];
        f32x4 st;
#pragma unroll
        for (int r = 0; r < 4; ++r) st[r] = ACC[rt][ct][r] + bo4[r];
        *(f32x4*)(orow + n0) = st;
      }
    }
  }
}

extern "C" void kernel_launch(void* const* d_in, const int* in_sizes, int n_in,
                              void* d_out, int out_size, void* d_ws, size_t ws_size,
                              hipStream_t stream) {
  const float* x       = (const float*)d_in[0];
  const float* w_qkv   = (const float*)d_in[1];
  const float* pos_emb = (const float*)d_in[2];
  const float* w_out   = (const float*)d_in[3];
  const float* b_out   = (const float*)d_in[4];
  float* out = (float*)d_out;

  unsigned short* wqkvT = (unsigned short*)d_ws;
  unsigned short* woutT = wqkvT + 768 * 256;
  float* bias64 = (float*)(woutT + 256 * 256);

  prep_kernel<<<96, 256, 0, stream>>>(w_qkv, w_out, pos_emb, wqkvT, woutT, bias64);
  winattn_kernel<<<2048, 256, 0, stream>>>(x, wqkvT, woutT, bias64, b_out, out);
}